// Round 7
// baseline (65.089 us; speedup 1.0000x reference)
//
#include <hip/hip_runtime.h>
#include <math.h>

// StructLoss: sqrt(mean(|grads4(outputs - labels)|) + 1e-16)
// grads4 linear -> compute on d = outputs - labels.
// [B=16, C=6, H=512, W=512] fp32; mean over B*4C*H*W.
//
// Flat register pipeline, no LDS tiles, no block barriers in the hot loop.
// One 64-lane wave owns a full 512-wide row (lane l -> cols 8l..8l+7) and
// walks a 16-row chunk. Depth-3 modulo schedule: iteration r issues loads
// for row r+3, converts (sub + shfl edges) row r+2 from loads issued last
// iteration, and stencils rows r-1,r,r+1 (converted >=2 iters ago) -- no
// value is consumed in the iteration that produces it. All guards are
// compile-time under full unroll; boundary rows use clamped addresses +
// 0/1 mask multiply. Final mean+sqrt fused via last-block atomic counter.

#define NTHREADS 256
#define CHUNK 16
#define WV 512
#define HT 512
#define PLANES 96
#define CHUNKS_PER_PLANE (HT / CHUNK)                    // 32
#define TOTAL_WAVES (PLANES * CHUNKS_PER_PLANE)          // 3072
#define NBLOCKS (TOTAL_WAVES / (NTHREADS / 64))          // 768 = 3 blocks/CU

struct Raw { float4 o0, o1, l0, l1; };
struct Row { float d[8]; float eL, eR; };

__device__ __forceinline__ Raw load_row(const float* __restrict__ ob,
                                        const float* __restrict__ lb, int r) {
    const int gr = min(max(r, 0), HT - 1);       // clamp: address always valid
    const size_t off = (size_t)gr * WV;
    Raw w;
    w.o0 = *reinterpret_cast<const float4*>(ob + off);
    w.o1 = *reinterpret_cast<const float4*>(ob + off + 4);
    w.l0 = *reinterpret_cast<const float4*>(lb + off);
    w.l1 = *reinterpret_cast<const float4*>(lb + off + 4);
    return w;
}

__device__ __forceinline__ Row convert(const Raw& w, int lane, float m) {
    Row row;
    row.d[0] = m * (w.o0.x - w.l0.x); row.d[1] = m * (w.o0.y - w.l0.y);
    row.d[2] = m * (w.o0.z - w.l0.z); row.d[3] = m * (w.o0.w - w.l0.w);
    row.d[4] = m * (w.o1.x - w.l1.x); row.d[5] = m * (w.o1.y - w.l1.y);
    row.d[6] = m * (w.o1.z - w.l1.z); row.d[7] = m * (w.o1.w - w.l1.w);
    const float up = __shfl_up(row.d[7], 1, 64);
    const float dn = __shfl_down(row.d[0], 1, 64);
    row.eL = (lane == 0)  ? 0.f : up;    // col 8l-1 (image zero-pad)
    row.eR = (lane == 63) ? 0.f : dn;    // col 8l+8 (image zero-pad)
    return row;
}

__device__ __forceinline__ float stencil(const Row& rp, const Row& rc,
                                         const Row& rn) {
    float a = 0.f;
    #pragma unroll
    for (int k = 0; k < 8; ++k) {
        const float cL = (k > 0) ? rc.d[k - 1] : rc.eL;
        const float cR = (k < 7) ? rc.d[k + 1] : rc.eR;
        const float pL = (k > 0) ? rp.d[k - 1] : rp.eL;
        const float pR = (k < 7) ? rp.d[k + 1] : rp.eR;
        const float nL = (k > 0) ? rn.d[k - 1] : rn.eL;
        const float nR = (k < 7) ? rn.d[k + 1] : rn.eR;

        const float gy = rp.d[k] - rn.d[k];   // x[i-1,j]   - x[i+1,j]
        const float gx = cL - cR;             // x[i,j-1]   - x[i,j+1]
        const float gD = pL - nR;             // x[i-1,j-1] - x[i+1,j+1]
        const float gd = pR - nL;             // x[i-1,j+1] - x[i+1,j-1]
        a += fabsf(gy) + fabsf(gx) + fabsf(gD) + fabsf(gd);
    }
    return a;
}

__global__ __launch_bounds__(NTHREADS) void struct_loss(
        const float* __restrict__ out_p, const float* __restrict__ lab_p,
        float* __restrict__ partials, unsigned* __restrict__ counter,
        float* __restrict__ out, double inv_count) {
    const int tid  = threadIdx.x;
    const int lane = tid & 63;
    const int wid  = tid >> 6;
    const int gw   = blockIdx.x * (NTHREADS / 64) + wid;   // 0..3071
    const int plane = gw >> 5;                             // / CHUNKS_PER_PLANE
    const int r0    = (gw & (CHUNKS_PER_PLANE - 1)) * CHUNK;

    const size_t base = (size_t)plane * (HT * WV) + lane * 8;
    const float* ob = out_p + base;
    const float* lb = lab_p + base;

    float acc = 0.f;

    // Pipeline prologue: rows r0-1 .. r0+2.
    Raw A = load_row(ob, lb, r0 - 1);
    Raw B = load_row(ob, lb, r0);
    Raw C = load_row(ob, lb, r0 + 1);
    Raw F = load_row(ob, lb, r0 + 2);           // in flight for first convert
    Row rp = convert(A, lane, (r0 > 0) ? 1.f : 0.f);
    Row rc = convert(B, lane, 1.f);
    Row rn = convert(C, lane, 1.f);
    Row rn2;
    Raw F2;

    #pragma unroll
    for (int rr = 0; rr < CHUNK; ++rr) {
        // Stage 3: issue loads for row r0+rr+3 (used 2 iterations later).
        if (rr <= CHUNK - 3) F2 = load_row(ob, lb, r0 + rr + 3);

        // Stage 1: stencil rows r0+rr-1 .. r0+rr+1 (all converted earlier).
        acc += stencil(rp, rc, rn);

        // Stage 2: convert row r0+rr+2 (loads issued last iteration).
        if (rr <= CHUNK - 2) {
            const float m = (r0 + rr + 2 < HT) ? 1.f : 0.f;
            rn2 = convert(F, lane, m);
        }

        // Rotate (guards compile-time; dead rotations dropped).
        rp = rc; rc = rn;
        if (rr <= CHUNK - 2) rn = rn2;
        if (rr <= CHUNK - 3) F = F2;
    }

    // ---- wave + block reduction ----
    #pragma unroll
    for (int off = 32; off > 0; off >>= 1)
        acc += __shfl_down(acc, off, 64);

    __shared__ float smem[NTHREADS / 64];
    if (lane == 0) smem[wid] = acc;
    __syncthreads();

    __shared__ bool amLast;
    if (tid == 0) {
        float s = 0.f;
        #pragma unroll
        for (int w = 0; w < NTHREADS / 64; ++w) s += smem[w];
        partials[blockIdx.x] = s;
        __threadfence();                          // publish partial
        const unsigned old = atomicAdd(counter, 1u);
        amLast = (old == (unsigned)(NBLOCKS - 1));
    }
    __syncthreads();

    if (amLast) {
        __threadfence();                          // see all partials
        double s = 0.0;
        // fixed-order, deterministic: 3 strided loads per thread
        for (int i = tid; i < NBLOCKS; i += NTHREADS)
            s += (double)partials[i];
        #pragma unroll
        for (int off = 32; off > 0; off >>= 1)
            s += __shfl_down(s, off, 64);
        __shared__ double dsm[NTHREADS / 64];
        if (lane == 0) dsm[wid] = s;
        __syncthreads();
        if (tid == 0) {
            double t = 0.0;
            #pragma unroll
            for (int w = 0; w < NTHREADS / 64; ++w) t += dsm[w];
            out[0] = (float)sqrt(t * inv_count + 1e-16);
        }
    }
}

extern "C" void kernel_launch(void* const* d_in, const int* in_sizes, int n_in,
                              void* d_out, int out_size, void* d_ws, size_t ws_size,
                              hipStream_t stream) {
    const float* outputs = (const float*)d_in[0];
    const float* labels  = (const float*)d_in[1];
    float* out = (float*)d_out;

    unsigned* counter = (unsigned*)d_ws;            // u32 at offset 0
    float* partials   = (float*)d_ws + 16;          // 768 floats at 64 B offset

    const double inv_count = 1.0 / (16.0 * 24.0 * 512.0 * 512.0);

    hipMemsetAsync(counter, 0, sizeof(unsigned), stream);
    struct_loss<<<NBLOCKS, NTHREADS, 0, stream>>>(outputs, labels, partials,
                                                  counter, out, inv_count);
}